// Round 5
// baseline (445.499 us; speedup 1.0000x reference)
//
#include <hip/hip_runtime.h>

#define B_   256
#define L_   1024
#define H_   256   // DEC_H == ENC_D
#define EMB_ 128
#define OUT_ 172

typedef float f32x4 __attribute__((ext_vector_type(4)));
typedef __bf16 bf16x8 __attribute__((ext_vector_type(8)));
typedef unsigned short us8 __attribute__((ext_vector_type(8)));

static __device__ __forceinline__ unsigned short f2bf(float f) {
    __bf16 h = (__bf16)f;                      // native v_cvt RNE
    return __builtin_bit_cast(unsigned short, h);
}
static __device__ __forceinline__ us8 pack8(float4 x0, float4 x1) {
    bf16x8 v;
    v[0]=(__bf16)x0.x; v[1]=(__bf16)x0.y; v[2]=(__bf16)x0.z; v[3]=(__bf16)x0.w;
    v[4]=(__bf16)x1.x; v[5]=(__bf16)x1.y; v[6]=(__bf16)x1.z; v[7]=(__bf16)x1.w;
    return __builtin_bit_cast(us8, v);
}
static __device__ __forceinline__ us8 cvt8(const float* __restrict__ p) {
    return pack8(*(const float4*)p, *(const float4*)(p + 4));
}
static __device__ __forceinline__ float tanh_fast(float x) {
    float e = __expf(2.f * x);
    return 1.f - 2.f * __builtin_amdgcn_rcpf(e + 1.f);
}
static __device__ __forceinline__ float sigm_fast(float x) {
    return __builtin_amdgcn_rcpf(1.f + __expf(-x));
}

// LDS-only barrier: drain lgkm (LDS ops) but leave global loads in flight.
// __syncthreads() would emit s_waitcnt vmcnt(0) and collapse the prefetch
// distance to zero every iteration. Legal here: cross-wave hazards are
// LDS-only; in-flight VMEM is read-only global traffic whose results the
// compiler guards with its own counted vmcnt at point-of-use.
static __device__ __forceinline__ void barrier_lgkm() {
    __builtin_amdgcn_sched_barrier(0);
    asm volatile("s_waitcnt lgkmcnt(0)" ::: "memory");
    __builtin_amdgcn_s_barrier();
    __builtin_amdgcn_sched_barrier(0);
}

// LDS tile row stride for 64x32 bf16 GEMM tiles (16B-aligned; minor conflicts ok)
#define TS 40

// ------------------------------------------------- K1: gates = [emb|o_t|h0] @ [W_ih|W_hh]^T + biases
// Software-pipelined: 1 lgkm-barrier/iter, double-buffered LDS, loads kc+1 in flight across barrier.
__global__ __launch_bounds__(256) void k_gates(
    const float* __restrict__ h0, const float* __restrict__ o_t,
    const int* __restrict__ lasttarget, const float* __restrict__ emb,
    const float* __restrict__ W_ih, const float* __restrict__ W_hh,
    const float* __restrict__ b_ih, const float* __restrict__ b_hh,
    float* __restrict__ gates)
{
    const int m0 = (blockIdx.x >> 4) * 64;
    const int n0 = (blockIdx.x & 15) * 64;
    const int tid = threadIdx.x;
    const int w = tid >> 6, lane = tid & 63, quad = lane >> 4, l15 = lane & 15;

    __shared__ __align__(16) unsigned short As[2][64 * TS];
    __shared__ __align__(16) unsigned short Bs[2][64 * TS];

    float bias[4];
    #pragma unroll
    for (int nt = 0; nt < 4; nt++) {
        int n = n0 + nt * 16 + l15;
        bias[nt] = b_ih[n] + b_hh[n];
    }

    f32x4 acc[4] = {{0,0,0,0},{0,0,0,0},{0,0,0,0},{0,0,0,0}};
    const int sm = tid >> 2, sk8 = (tid & 3) * 8;
    const int lt = lasttarget[m0 + sm];
    const int j  = n0 + sm;

    // prologue: tile 0 -> regs (k = sk8 < 128 -> emb; B from W_ih)
    float4 xa0, xa1, xb0, xb1;
    {
        const float* ap = emb + lt * EMB_ + sk8;
        xa0 = *(const float4*)ap; xa1 = *(const float4*)(ap + 4);
        const float* bp = W_ih + j * 384 + sk8;
        xb0 = *(const float4*)bp; xb1 = *(const float4*)(bp + 4);
    }

    for (int kc = 0; kc < 20; kc++) {
        const int buf = kc & 1;
        // write tile kc (regs) into LDS
        *(us8*)&As[buf][sm * TS + sk8] = pack8(xa0, xa1);
        *(us8*)&Bs[buf][sm * TS + sk8] = pack8(xb0, xb1);
        // issue loads for tile kc+1
        float4 ya0 = {0,0,0,0}, ya1 = {0,0,0,0}, yb0 = {0,0,0,0}, yb1 = {0,0,0,0};
        if (kc < 19) {
            const int k = (kc + 1) * 32 + sk8;
            const float* ap;
            if (k < 128)      ap = emb + lt * EMB_ + k;
            else if (k < 384) ap = o_t + (m0 + sm) * H_ + (k - 128);
            else              ap = h0  + (m0 + sm) * H_ + (k - 384);
            ya0 = *(const float4*)ap; ya1 = *(const float4*)(ap + 4);
            const float* bp = (k < 384) ? (W_ih + j * 384 + k) : (W_hh + j * 256 + (k - 384));
            yb0 = *(const float4*)bp; yb1 = *(const float4*)(bp + 4);
        }
        barrier_lgkm();
        bf16x8 a = __builtin_bit_cast(bf16x8, *(const us8*)&As[buf][(w * 16 + l15) * TS + quad * 8]);
        #pragma unroll
        for (int nt = 0; nt < 4; nt++) {
            bf16x8 b = __builtin_bit_cast(bf16x8, *(const us8*)&Bs[buf][(nt * 16 + l15) * TS + quad * 8]);
            acc[nt] = __builtin_amdgcn_mfma_f32_16x16x32_bf16(a, b, acc[nt], 0, 0, 0);
        }
        xa0 = ya0; xa1 = ya1; xb0 = yb0; xb1 = yb1;
    }
    #pragma unroll
    for (int nt = 0; nt < 4; nt++)
        #pragma unroll
        for (int r = 0; r < 4; r++)
            gates[(m0 + w * 16 + quad * 4 + r) * 1024 + n0 + nt * 16 + l15] = acc[nt][r] + bias[nt];
}

// ------------------------------------------------- K2: LSTM pointwise + fused hW2 = h @ W2^T
__global__ __launch_bounds__(256) void k_lstm(
    const float* __restrict__ gates, const float* __restrict__ c0,
    const float* __restrict__ W2,
    float* __restrict__ out, unsigned short* __restrict__ A3u,
    float* __restrict__ hW2)
{
    const int b = blockIdx.x, t = threadIdx.x;
    const float* g = gates + b * 1024;
    float gi = g[t], gf = g[256 + t], gg = g[512 + t], go = g[768 + t];
    float c = sigm_fast(gf) * c0[b * H_ + t] + sigm_fast(gi) * tanh_fast(gg);
    float h = sigm_fast(go) * tanh_fast(c);
    out[b * H_ + t]           = h;   // h_t
    out[B_ * H_ + b * H_ + t] = c;   // c_t
    A3u[b * 256 + t] = f2bf(h);      // bf16 h for W3 GEMM

    __shared__ float hs[256];
    hs[t] = h;
    barrier_lgkm();                  // W2 row loads may stay in flight
    float acc = 0.f;
    const float* w2r = W2 + t * 256;
    #pragma unroll 4
    for (int k = 0; k < 256; k += 8) {
        float4 wa = *(const float4*)(w2r + k);
        float4 wb = *(const float4*)(w2r + k + 4);
        acc += hs[k]*wa.x + hs[k+1]*wa.y + hs[k+2]*wa.z + hs[k+3]*wa.w
             + hs[k+4]*wb.x + hs[k+5]*wb.y + hs[k+6]*wb.z + hs[k+7]*wb.w;
    }
    hW2[b * 256 + t] = acc;
}

// ------------------------------------------------- K3: fused attention, 2 blocks per batch (512 rows each)
// 32-row tiles (was 16): windows 34 -> 18, halving barrier/drain serialization.
// 4 x 32-row LDS buffers; live set per window {it (MFMA), it-2 (ctx), it+1 (write)}
// distinct mod 4. Write of tile it+1 at TOP of window (frees x regs before y loads).
// sp/wexp parity double-buffer as before. (512,2): <=128 VGPR, 2 blocks/CU,
// LDS 74 KB/block -> 148/160 KB. ((512,4) measured: 64-VGPR tier + 27MB spill.)
#define ROWSTR 264   // 256 bf16 + 8 pad
#define ATILES 16    // 16 tiles x 32 rows = 512 rows per block

__global__ __launch_bounds__(512, 2) void k_attn(
    const float* __restrict__ enc, const float* __restrict__ W1,
    const float* __restrict__ hW2, const float* __restrict__ beta,
    float* __restrict__ ctx_part, float* __restrict__ s_part)
{
    const int blk = blockIdx.x;
    const int b = blk >> 1, half = blk & 1;
    const int tid = threadIdx.x;
    const int wave = tid >> 6, lane = tid & 63;
    const int quad = lane >> 4, l15 = lane & 15;

    __shared__ __align__(16) unsigned short encs[4][32 * ROWSTR];
    __shared__ float sp[2][8][32];
    __shared__ float wexp[2][32];
    __shared__ float2 cr[512];

    // W1 B-fragments resident: wave covers cols [wave*32, wave*32+32)
    bf16x8 wf[8][2];
    float hw2v[2], betav[2];
    #pragma unroll
    for (int nt = 0; nt < 2; nt++) {
        int n = wave * 32 + nt * 16 + l15;
        hw2v[nt]  = hW2[b * H_ + n];
        betav[nt] = beta[n];
        #pragma unroll
        for (int ks = 0; ks < 8; ks++)
            wf[ks][nt] = __builtin_bit_cast(bf16x8, cvt8(W1 + n * 256 + ks * 32 + quad * 8));
    }

    const float* encb = enc + ((size_t)b * L_ + half * 512) * H_;
    const int srow = tid >> 4, scol = (tid & 15) * 16;   // 32 rows x 256 cols, 16 f32/thread

    // prologue: tile 0 -> buf 0 (direct); tile 1 -> regs
    {
        const float* p = encb + srow * 256 + scol;
        *(us8*)&encs[0][srow * ROWSTR + scol]     = cvt8(p);
        *(us8*)&encs[0][srow * ROWSTR + scol + 8] = cvt8(p + 8);
    }
    float4 x0, x1, x2, x3;
    {
        const float* p = encb + 32 * 256 + srow * 256 + scol;
        x0 = *(const float4*)p;       x1 = *(const float4*)(p + 4);
        x2 = *(const float4*)(p + 8); x3 = *(const float4*)(p + 12);
    }
    barrier_lgkm();

    const int cp = tid & 127, q = tid >> 7;   // ctx: col-pair, row-eighth-group
    float2 ctx2 = {0.f, 0.f};
    float ssum = 0.f;

    for (int it = 0; it < ATILES + 2; it++) {
        // (c) write tile it+1 (regs, loaded last window) into buf (it+1)&3 — early, frees x
        if (it < ATILES - 1) {
            *(us8*)&encs[(it + 1) & 3][srow * ROWSTR + scol]     = pack8(x0, x1);
            *(us8*)&encs[(it + 1) & 3][srow * ROWSTR + scol + 8] = pack8(x2, x3);
        }
        // (a) issue loads for tile it+2
        float4 y0 = {0,0,0,0}, y1 = {0,0,0,0}, y2 = {0,0,0,0}, y3 = {0,0,0,0};
        if (it < ATILES - 2) {
            const float* p = encb + (size_t)(it + 2) * 32 * 256 + srow * 256 + scol;
            y0 = *(const float4*)p;       y1 = *(const float4*)(p + 4);
            y2 = *(const float4*)(p + 8); y3 = *(const float4*)(p + 12);
        }
        // (e) wexp for tile it-1 (sp written last window, visible after barrier)
        if (it >= 1 && it <= ATILES && tid < 32) {
            const int pp = (it - 1) & 1;
            float sc = sp[pp][0][tid] + sp[pp][1][tid] + sp[pp][2][tid] + sp[pp][3][tid]
                     + sp[pp][4][tid] + sp[pp][5][tid] + sp[pp][6][tid] + sp[pp][7][tid];
            wexp[pp][tid] = __expf(sc);
        }
        // (f) ctx for tile it-2 (wexp written last window) + ssum
        if (it >= 2) {
            const int pb = (it - 2) & 3, pp = (it - 2) & 1;
            const unsigned* base = (const unsigned*)&encs[pb][0];
            float cx = ctx2.x, cy = ctx2.y;
            #pragma unroll
            for (int r = 0; r < 8; r++) {
                const int row = q * 8 + r;
                unsigned u = base[row * (ROWSTR / 2) + cp];
                float wv = wexp[pp][row];   // wave-uniform -> broadcast
                cx += wv * __uint_as_float(u << 16);
                cy += wv * __uint_as_float(u & 0xffff0000u);
            }
            ctx2.x = cx; ctx2.y = cy;
            if (tid == 0) {
                float s2 = 0.f;
                #pragma unroll
                for (int r = 0; r < 32; r++) s2 += wexp[pp][r];
                ssum += s2;
            }
        }
        // (b,d) MFMA + score partials for tile it, two 16-row sub-tiles
        if (it < ATILES) {
            #pragma unroll
            for (int sub = 0; sub < 2; sub++) {
                f32x4 acc0 = {0,0,0,0}, acc1 = {0,0,0,0};
                const unsigned short* arow = &encs[it & 3][(sub * 16 + l15) * ROWSTR + quad * 8];
                #pragma unroll
                for (int ks = 0; ks < 8; ks++) {
                    bf16x8 a = __builtin_bit_cast(bf16x8, *(const us8*)(arow + ks * 32));
                    acc0 = __builtin_amdgcn_mfma_f32_16x16x32_bf16(a, wf[ks][0], acc0, 0, 0, 0);
                    acc1 = __builtin_amdgcn_mfma_f32_16x16x32_bf16(a, wf[ks][1], acc1, 0, 0, 0);
                }
                float p4[4];
                #pragma unroll
                for (int r = 0; r < 4; r++) {
                    float t0 = tanh_fast(acc0[r] + hw2v[0]);
                    float t1 = tanh_fast(acc1[r] + hw2v[1]);
                    p4[r] = betav[0] * t0 + betav[1] * t1;
                }
                #pragma unroll
                for (int m = 1; m < 16; m <<= 1) {
                    p4[0] += __shfl_xor(p4[0], m);
                    p4[1] += __shfl_xor(p4[1], m);
                    p4[2] += __shfl_xor(p4[2], m);
                    p4[3] += __shfl_xor(p4[3], m);
                }
                if (l15 == 0) {
                    #pragma unroll
                    for (int r = 0; r < 4; r++) sp[it & 1][wave][sub * 16 + quad * 4 + r] = p4[r];
                }
            }
        }
        barrier_lgkm();
        x0 = y0; x1 = y1; x2 = y2; x3 = y3;
    }
    cr[tid] = ctx2;
    barrier_lgkm();
    if (tid == 0) s_part[blk] = ssum;
    if (tid < 128) {
        float2 a0 = cr[tid], a1 = cr[tid + 128], a2 = cr[tid + 256], a3 = cr[tid + 384];
        float2 o;
        o.x = a0.x + a1.x + a2.x + a3.x;
        o.y = a0.y + a1.y + a2.y + a3.y;
        ((float2*)ctx_part)[blk * 128 + tid] = o;   // cols 2t, 2t+1 (unnormalized)
    }
}

// ------------------------------------------------- K4: o_new = tanh([h|ctx] @ W3^T)  (M=256 N=256 K=512), grid 16
// ctx combine fused into A-staging; software-pipelined, 1 lgkm-barrier/iter.
__global__ __launch_bounds__(256) void k_out3(
    const unsigned short* __restrict__ A3u, const float* __restrict__ ctx_part,
    const float* __restrict__ s_part, const float* __restrict__ W3,
    float* __restrict__ out, unsigned short* __restrict__ A4u)
{
    const int m0 = (blockIdx.x >> 2) * 64;
    const int n0 = (blockIdx.x & 3) * 64;
    const int tid = threadIdx.x;
    const int w = tid >> 6, lane = tid & 63, quad = lane >> 4, l15 = lane & 15;
    __shared__ __align__(16) unsigned short As[2][64 * TS];
    __shared__ __align__(16) unsigned short Bs[2][64 * TS];
    f32x4 acc[4] = {{0,0,0,0},{0,0,0,0},{0,0,0,0},{0,0,0,0}};
    const int sm = tid >> 2, sk8 = (tid & 3) * 8;
    const int bb = m0 + sm;
    const float inv = 1.f / (s_part[2 * bb] + s_part[2 * bb + 1]);

    // prologue: tile 0 (k = sk8 < 256 -> A3u path)
    us8 au = *(const us8*)&A3u[bb * 256 + sk8];
    float4 ca0, ca1, cb0, cb1;               // ctx prefetch (kc >= 8)
    float4 wb0, wb1;
    { const float* bp = W3 + (n0 + sm) * 512 + sk8;
      wb0 = *(const float4*)bp; wb1 = *(const float4*)(bp + 4); }

    for (int kc = 0; kc < 16; kc++) {
        const int buf = kc & 1;
        // write tile kc
        if (kc < 8) {
            *(us8*)&As[buf][sm * TS + sk8] = au;
        } else {
            bf16x8 v;
            v[0]=(__bf16)((ca0.x+cb0.x)*inv); v[1]=(__bf16)((ca0.y+cb0.y)*inv);
            v[2]=(__bf16)((ca0.z+cb0.z)*inv); v[3]=(__bf16)((ca0.w+cb0.w)*inv);
            v[4]=(__bf16)((ca1.x+cb1.x)*inv); v[5]=(__bf16)((ca1.y+cb1.y)*inv);
            v[6]=(__bf16)((ca1.z+cb1.z)*inv); v[7]=(__bf16)((ca1.w+cb1.w)*inv);
            *(us8*)&As[buf][sm * TS + sk8] = __builtin_bit_cast(us8, v);
        }
        *(us8*)&Bs[buf][sm * TS + sk8] = pack8(wb0, wb1);
        // prefetch tile kc+1
        if (kc < 15) {
            const int k = (kc + 1) * 32 + sk8;
            if (kc + 1 < 8) {
                au = *(const us8*)&A3u[bb * 256 + k];
            } else {
                const int c = k - 256;
                const float* p0 = ctx_part + (size_t)(2 * bb) * 256 + c;
                const float* p1 = ctx_part + (size_t)(2 * bb + 1) * 256 + c;
                ca0 = *(const float4*)p0; ca1 = *(const float4*)(p0 + 4);
                cb0 = *(const float4*)p1; cb1 = *(const float4*)(p1 + 4);
            }
            const float* bp = W3 + (n0 + sm) * 512 + k;
            wb0 = *(const float4*)bp; wb1 = *(const float4*)(bp + 4);
        }
        barrier_lgkm();
        bf16x8 a = __builtin_bit_cast(bf16x8, *(const us8*)&As[buf][(w * 16 + l15) * TS + quad * 8]);
        #pragma unroll
        for (int nt = 0; nt < 4; nt++) {
            bf16x8 b = __builtin_bit_cast(bf16x8, *(const us8*)&Bs[buf][(nt * 16 + l15) * TS + quad * 8]);
            acc[nt] = __builtin_amdgcn_mfma_f32_16x16x32_bf16(a, b, acc[nt], 0, 0, 0);
        }
    }
    #pragma unroll
    for (int nt = 0; nt < 4; nt++)
        #pragma unroll
        for (int r = 0; r < 4; r++) {
            int row = m0 + w * 16 + quad * 4 + r, col = n0 + nt * 16 + l15;
            float o = tanh_fast(acc[nt][r]);
            out[2 * B_ * H_ + row * 256 + col] = o;   // o_new
            A4u[row * 256 + col] = f2bf(o);
        }
}

// ------------------------------------------------- K5: logit = softmax(o_new @ W_out^T), grid 4
// software-pipelined, 1 lgkm-barrier/iter.
__global__ __launch_bounds__(256) void k_logit(
    const unsigned short* __restrict__ A4u, const float* __restrict__ W_out,
    float* __restrict__ out)
{
    const int m0 = blockIdx.x * 64;
    const int tid = threadIdx.x;
    const int w = tid >> 6, lane = tid & 63, quad = lane >> 4, l15 = lane & 15;
    __shared__ __align__(16) unsigned short As[2][64 * TS];
    __shared__ __align__(16) unsigned short Bs[2][192 * TS];
    __shared__ float lg[64][196];
    f32x4 acc[12];
    #pragma unroll
    for (int nt = 0; nt < 12; nt++) acc[nt] = (f32x4){0,0,0,0};
    const int sm = tid >> 2, sk8 = (tid & 3) * 8;
    const int j0 = sm, j1 = 64 + sm, j2 = 128 + sm;   // j2 < 172 may fail

    us8 au = *(const us8*)&A4u[(m0 + sm) * 256 + sk8];
    float4 w0a, w0b, w1a, w1b, w2a = {0,0,0,0}, w2b = {0,0,0,0};
    { const float* p = W_out + j0 * 256 + sk8; w0a = *(const float4*)p; w0b = *(const float4*)(p + 4); }
    { const float* p = W_out + j1 * 256 + sk8; w1a = *(const float4*)p; w1b = *(const float4*)(p + 4); }
    if (j2 < OUT_) { const float* p = W_out + j2 * 256 + sk8; w2a = *(const float4*)p; w2b = *(const float4*)(p + 4); }

    for (int kc = 0; kc < 8; kc++) {
        const int buf = kc & 1;
        *(us8*)&As[buf][sm * TS + sk8] = au;
        *(us8*)&Bs[buf][j0 * TS + sk8] = pack8(w0a, w0b);
        *(us8*)&Bs[buf][j1 * TS + sk8] = pack8(w1a, w1b);
        *(us8*)&Bs[buf][j2 * TS + sk8] = pack8(w2a, w2b);   // zeros when j2 >= OUT_
        if (kc < 7) {
            const int k = (kc + 1) * 32 + sk8;
            au = *(const us8*)&A4u[(m0 + sm) * 256 + k];
            { const float* p = W_out + j0 * 256 + k; w0a = *(const float4*)p; w0b = *(const float4*)(p + 4); }
            { const float* p = W_out + j1 * 256 + k; w1a = *(const float4*)p; w1b = *(const float4*)(p + 4); }
            if (j2 < OUT_) { const float* p = W_out + j2 * 256 + k; w2a = *(const float4*)p; w2b = *(const float4*)(p + 4); }
        }
        barrier_lgkm();
        bf16x8 a = __builtin_bit_cast(bf16x8, *(const us8*)&As[buf][(w * 16 + l15) * TS + quad * 8]);
        #pragma unroll
        for (int nt = 0; nt < 12; nt++) {
            bf16x8 b = __builtin_bit_cast(bf16x8, *(const us8*)&Bs[buf][(nt * 16 + l15) * TS + quad * 8]);
            acc[nt] = __builtin_amdgcn_mfma_f32_16x16x32_bf16(a, b, acc[nt], 0, 0, 0);
        }
    }
    #pragma unroll
    for (int nt = 0; nt < 12; nt++)
        #pragma unroll
        for (int r = 0; r < 4; r++)
            lg[w * 16 + quad * 4 + r][nt * 16 + l15] = acc[nt][r];
    __syncthreads();
    const int m = tid >> 2, p = tid & 3;
    const int cb = p * 43;
    float mx = -1e30f;
    for (int c = 0; c < 43; c++) mx = fmaxf(mx, lg[m][cb + c]);
    mx = fmaxf(mx, __shfl_xor(mx, 1));
    mx = fmaxf(mx, __shfl_xor(mx, 2));
    float s = 0.f;
    for (int c = 0; c < 43; c++) { float e = __expf(lg[m][cb + c] - mx); lg[m][cb + c] = e; s += e; }
    s += __shfl_xor(s, 1);
    s += __shfl_xor(s, 2);
    float inv = 1.f / s;
    for (int c = 0; c < 43; c++)
        out[3 * B_ * H_ + (m0 + m) * OUT_ + cb + c] = lg[m][cb + c] * inv;
}

// ------------------------------------------------- host
extern "C" void kernel_launch(void* const* d_in, const int* in_sizes, int n_in,
                              void* d_out, int out_size, void* d_ws, size_t ws_size,
                              hipStream_t stream)
{
    const float* h0   = (const float*)d_in[0];
    const float* c0   = (const float*)d_in[1];
    const float* o_t  = (const float*)d_in[2];
    const float* enc  = (const float*)d_in[3];
    const int*   lt   = (const int*)  d_in[4];
    const float* emb  = (const float*)d_in[5];
    const float* W_ih = (const float*)d_in[6];
    const float* W_hh = (const float*)d_in[7];
    const float* b_ih = (const float*)d_in[8];
    const float* b_hh = (const float*)d_in[9];
    const float* W1   = (const float*)d_in[10];
    const float* W2   = (const float*)d_in[11];
    const float* W3   = (const float*)d_in[12];
    const float* Wo   = (const float*)d_in[13];
    const float* beta = (const float*)d_in[14];
    float* out = (float*)d_out;
    float* ws  = (float*)d_ws;

    float*          gates    = ws;                               // 256*1024 f32
    float*          hW2      = ws + 262144;                      // 256*256 f32
    float*          ctx_part = ws + 327680;                      // 512*256 f32
    float*          s_part   = ws + 458752;                      // 512 f32
    unsigned short* A3u      = (unsigned short*)(ws + 459264);   // 256*256 bf16 (h)
    unsigned short* A4u      = (unsigned short*)(ws + 492032);   // 256*256 bf16 (o_new)

    k_gates<<<64, 256, 0, stream>>>(h0, o_t, lt, emb, W_ih, W_hh, b_ih, b_hh, gates);
    k_lstm <<<256, 256, 0, stream>>>(gates, c0, W2, out, A3u, hW2);
    k_attn <<<512, 512, 0, stream>>>(enc, W1, hW2, beta, ctx_part, s_part);
    k_out3 <<<16, 256, 0, stream>>>(A3u, ctx_part, s_part, W3, out, A4u);
    k_logit<<<4, 256, 0, stream>>>(A4u, Wo, out);
}

// Round 6
// 437.166 us; speedup vs baseline: 1.0191x; 1.0191x over previous
//
#include <hip/hip_runtime.h>

#define B_   256
#define L_   1024
#define H_   256   // DEC_H == ENC_D
#define EMB_ 128
#define OUT_ 172

typedef float f32x4 __attribute__((ext_vector_type(4)));
typedef __bf16 bf16x8 __attribute__((ext_vector_type(8)));
typedef unsigned short us8 __attribute__((ext_vector_type(8)));

static __device__ __forceinline__ unsigned short f2bf(float f) {
    __bf16 h = (__bf16)f;                      // native v_cvt RNE
    return __builtin_bit_cast(unsigned short, h);
}
static __device__ __forceinline__ us8 pack8(float4 x0, float4 x1) {
    bf16x8 v;
    v[0]=(__bf16)x0.x; v[1]=(__bf16)x0.y; v[2]=(__bf16)x0.z; v[3]=(__bf16)x0.w;
    v[4]=(__bf16)x1.x; v[5]=(__bf16)x1.y; v[6]=(__bf16)x1.z; v[7]=(__bf16)x1.w;
    return __builtin_bit_cast(us8, v);
}
static __device__ __forceinline__ us8 cvt8(const float* __restrict__ p) {
    return pack8(*(const float4*)p, *(const float4*)(p + 4));
}
static __device__ __forceinline__ float tanh_fast(float x) {
    float e = __expf(2.f * x);
    return 1.f - 2.f * __builtin_amdgcn_rcpf(e + 1.f);
}
static __device__ __forceinline__ float sigm_fast(float x) {
    return __builtin_amdgcn_rcpf(1.f + __expf(-x));
}

// LDS-only barrier: drain lgkm (LDS ops) but leave global loads in flight.
// __syncthreads() would emit s_waitcnt vmcnt(0) and collapse the prefetch
// distance to zero every iteration. Legal here: cross-wave hazards are
// LDS-only; in-flight VMEM is read-only global traffic whose results the
// compiler guards with its own counted vmcnt at point-of-use.
static __device__ __forceinline__ void barrier_lgkm() {
    __builtin_amdgcn_sched_barrier(0);
    asm volatile("s_waitcnt lgkmcnt(0)" ::: "memory");
    __builtin_amdgcn_s_barrier();
    __builtin_amdgcn_sched_barrier(0);
}

// LDS tile row strides (16B-aligned; ~2-way bank aliasing = free)
#define TS  40   // 32-wide k tiles
#define TS2 72   // 64-wide k tiles

// ------------------------------------------------- K1: gates = [emb|o_t|h0] @ [W_ih|W_hh]^T + biases
// BK=64: 10 windows (was 20). Window k-ranges are 64-aligned; source switches
// (emb->o_t at 128, o_t->h0 / W_ih->W_hh at 384) are 64-multiples -> every
// window is source-pure. Stage-before-load ordering reuses one register set.
__global__ __launch_bounds__(256) void k_gates(
    const float* __restrict__ h0, const float* __restrict__ o_t,
    const int* __restrict__ lasttarget, const float* __restrict__ emb,
    const float* __restrict__ W_ih, const float* __restrict__ W_hh,
    const float* __restrict__ b_ih, const float* __restrict__ b_hh,
    float* __restrict__ gates)
{
    const int m0 = (blockIdx.x >> 4) * 64;
    const int n0 = (blockIdx.x & 15) * 64;
    const int tid = threadIdx.x;
    const int w = tid >> 6, lane = tid & 63, quad = lane >> 4, l15 = lane & 15;

    __shared__ __align__(16) unsigned short As[2][64 * TS2];
    __shared__ __align__(16) unsigned short Bs[2][64 * TS2];

    float bias[4];
    #pragma unroll
    for (int nt = 0; nt < 4; nt++) {
        int n = n0 + nt * 16 + l15;
        bias[nt] = b_ih[n] + b_hh[n];
    }

    f32x4 acc[4] = {{0,0,0,0},{0,0,0,0},{0,0,0,0},{0,0,0,0}};
    const int sm = tid >> 2, sk8 = (tid & 3) * 8;
    const int row = m0 + sm;
    const int lt = lasttarget[row];
    const int j  = n0 + sm;

    // prologue: window 0 (k in [0,64): A from emb, B from W_ih)
    float4 xa0, xa1, xa2, xa3, xb0, xb1, xb2, xb3;
    {
        const float* a0 = emb + lt * EMB_ + sk8;
        const float* a1 = a0 + 32;
        xa0 = *(const float4*)a0; xa1 = *(const float4*)(a0 + 4);
        xa2 = *(const float4*)a1; xa3 = *(const float4*)(a1 + 4);
        const float* b0 = W_ih + j * 384 + sk8;
        const float* b1 = b0 + 32;
        xb0 = *(const float4*)b0; xb1 = *(const float4*)(b0 + 4);
        xb2 = *(const float4*)b1; xb3 = *(const float4*)(b1 + 4);
    }

    for (int kc = 0; kc < 10; kc++) {
        const int buf = kc & 1;
        // stage window kc (regs loaded last iter)
        *(us8*)&As[buf][sm * TS2 + sk8]      = pack8(xa0, xa1);
        *(us8*)&As[buf][sm * TS2 + 32 + sk8] = pack8(xa2, xa3);
        *(us8*)&Bs[buf][sm * TS2 + sk8]      = pack8(xb0, xb1);
        *(us8*)&Bs[buf][sm * TS2 + 32 + sk8] = pack8(xb2, xb3);
        // issue loads for window kc+1 (in flight across the barrier)
        if (kc < 9) {
            const int k0 = (kc + 1) * 64 + sk8;
            const int k1 = k0 + 32;
            const float* a0 = (k0 < 128) ? emb + lt * EMB_ + k0
                            : (k0 < 384) ? o_t + row * H_ + (k0 - 128)
                                         : h0  + row * H_ + (k0 - 384);
            const float* a1 = (k1 < 128) ? emb + lt * EMB_ + k1
                            : (k1 < 384) ? o_t + row * H_ + (k1 - 128)
                                         : h0  + row * H_ + (k1 - 384);
            xa0 = *(const float4*)a0; xa1 = *(const float4*)(a0 + 4);
            xa2 = *(const float4*)a1; xa3 = *(const float4*)(a1 + 4);
            const float* b0 = (k0 < 384) ? W_ih + j * 384 + k0 : W_hh + j * 256 + (k0 - 384);
            const float* b1 = (k1 < 384) ? W_ih + j * 384 + k1 : W_hh + j * 256 + (k1 - 384);
            xb0 = *(const float4*)b0; xb1 = *(const float4*)(b0 + 4);
            xb2 = *(const float4*)b1; xb3 = *(const float4*)(b1 + 4);
        }
        barrier_lgkm();
        #pragma unroll
        for (int c = 0; c < 2; c++) {
            bf16x8 a = __builtin_bit_cast(bf16x8, *(const us8*)&As[buf][(w * 16 + l15) * TS2 + c * 32 + quad * 8]);
            #pragma unroll
            for (int nt = 0; nt < 4; nt++) {
                bf16x8 b = __builtin_bit_cast(bf16x8, *(const us8*)&Bs[buf][(nt * 16 + l15) * TS2 + c * 32 + quad * 8]);
                acc[nt] = __builtin_amdgcn_mfma_f32_16x16x32_bf16(a, b, acc[nt], 0, 0, 0);
            }
        }
    }
    #pragma unroll
    for (int nt = 0; nt < 4; nt++)
        #pragma unroll
        for (int r = 0; r < 4; r++)
            gates[(m0 + w * 16 + quad * 4 + r) * 1024 + n0 + nt * 16 + l15] = acc[nt][r] + bias[nt];
}

// ------------------------------------------------- K2: LSTM pointwise + fused hW2 = h @ W2^T
__global__ __launch_bounds__(256) void k_lstm(
    const float* __restrict__ gates, const float* __restrict__ c0,
    const float* __restrict__ W2,
    float* __restrict__ out, unsigned short* __restrict__ A3u,
    float* __restrict__ hW2)
{
    const int b = blockIdx.x, t = threadIdx.x;
    const float* g = gates + b * 1024;
    float gi = g[t], gf = g[256 + t], gg = g[512 + t], go = g[768 + t];
    float c = sigm_fast(gf) * c0[b * H_ + t] + sigm_fast(gi) * tanh_fast(gg);
    float h = sigm_fast(go) * tanh_fast(c);
    out[b * H_ + t]           = h;   // h_t
    out[B_ * H_ + b * H_ + t] = c;   // c_t
    A3u[b * 256 + t] = f2bf(h);      // bf16 h for W3 GEMM

    __shared__ float hs[256];
    hs[t] = h;
    barrier_lgkm();                  // W2 row loads may stay in flight
    float acc = 0.f;
    const float* w2r = W2 + t * 256;
    #pragma unroll 4
    for (int k = 0; k < 256; k += 8) {
        float4 wa = *(const float4*)(w2r + k);
        float4 wb = *(const float4*)(w2r + k + 4);
        acc += hs[k]*wa.x + hs[k+1]*wa.y + hs[k+2]*wa.z + hs[k+3]*wa.w
             + hs[k+4]*wb.x + hs[k+5]*wb.y + hs[k+6]*wb.z + hs[k+7]*wb.w;
    }
    hW2[b * 256 + t] = acc;
}

// ------------------------------------------------- K3: fused attention, 2 blocks per batch (512 rows each)
// ROUND-4 VERSION (best measured, 440.7 us total). 16-row tiles, 4-buffer
// pipeline, ONE lgkm-only barrier per tile; prefetch loads survive the barrier.
// 32-row variant measured NEUTRAL (round 5) -> window count is not the limiter;
// this kernel is near its HBM stream floor (~48 us). Do not re-tune barriers.
// (512,2): <=128 VGPR, 2 blocks/CU. ((512,4) measured: 64-VGPR tier + 27MB spill.)
#define ROWSTR 264   // 256 bf16 + 8 pad

__global__ __launch_bounds__(512, 2) void k_attn(
    const float* __restrict__ enc, const float* __restrict__ W1,
    const float* __restrict__ hW2, const float* __restrict__ beta,
    float* __restrict__ ctx_part, float* __restrict__ s_part)
{
    const int blk = blockIdx.x;
    const int b = blk >> 1, half = blk & 1;
    const int tid = threadIdx.x;
    const int wave = tid >> 6, lane = tid & 63;
    const int quad = lane >> 4, l15 = lane & 15;

    __shared__ __align__(16) unsigned short encs[4][16 * ROWSTR];
    __shared__ float sp[2][8][16];
    __shared__ float wexp[2][16];
    __shared__ float2 cr[512];

    // W1 B-fragments resident: wave covers cols [wave*32, wave*32+32)
    bf16x8 wf[8][2];
    float hw2v[2], betav[2];
    #pragma unroll
    for (int nt = 0; nt < 2; nt++) {
        int n = wave * 32 + nt * 16 + l15;
        hw2v[nt]  = hW2[b * H_ + n];
        betav[nt] = beta[n];
        #pragma unroll
        for (int ks = 0; ks < 8; ks++)
            wf[ks][nt] = __builtin_bit_cast(bf16x8, cvt8(W1 + n * 256 + ks * 32 + quad * 8));
    }

    const float* encb = enc + ((size_t)b * L_ + half * 512) * H_;
    const int srow = tid >> 5, scol = (tid & 31) * 8;

    // prologue: tile 0 -> buf 0; tile 1 -> regs
    *(us8*)&encs[0][srow * ROWSTR + scol] = cvt8(encb + srow * 256 + scol);
    float4 x0, x1;
    {
        const float* p = encb + 16 * 256 + srow * 256 + scol;
        x0 = *(const float4*)p; x1 = *(const float4*)(p + 4);
    }
    barrier_lgkm();

    const int cp = tid & 127, q = tid >> 7;   // ctx: col-pair, row-quarter
    float2 ctx2 = {0.f, 0.f};
    float ssum = 0.f;

    for (int it = 0; it < 34; it++) {
        // (a) issue loads for tile it+2
        float4 y0 = {0,0,0,0}, y1 = {0,0,0,0};
        if (it < 30) {
            const float* p = encb + (size_t)(it + 2) * 16 * 256 + srow * 256 + scol;
            y0 = *(const float4*)p; y1 = *(const float4*)(p + 4);
        }
        // (e) wexp for tile it-1 (sp written last window, visible after barrier)
        if (it >= 1 && it <= 32 && tid < 16) {
            const int pp = (it - 1) & 1;
            float sc = sp[pp][0][tid] + sp[pp][1][tid] + sp[pp][2][tid] + sp[pp][3][tid]
                     + sp[pp][4][tid] + sp[pp][5][tid] + sp[pp][6][tid] + sp[pp][7][tid];
            wexp[pp][tid] = __expf(sc);
        }
        // (f) ctx for tile it-2 (wexp written last window) + ssum
        if (it >= 2) {
            const int pb = (it - 2) & 3, pp = (it - 2) & 1;
            const unsigned* base = (const unsigned*)&encs[pb][0];
            float cx = ctx2.x, cy = ctx2.y;
            #pragma unroll
            for (int r = 0; r < 4; r++) {
                const int row = q * 4 + r;
                unsigned u = base[row * (ROWSTR / 2) + cp];
                float wv = wexp[pp][row];   // wave-uniform -> broadcast
                cx += wv * __uint_as_float(u << 16);
                cy += wv * __uint_as_float(u & 0xffff0000u);
            }
            ctx2.x = cx; ctx2.y = cy;
            if (tid == 0) {
                float s2 = 0.f;
                #pragma unroll
                for (int r = 0; r < 16; r++) s2 += wexp[pp][r];
                ssum += s2;
            }
        }
        // (b,d) MFMA + score partials for tile it
        if (it < 32) {
            f32x4 acc0 = {0,0,0,0}, acc1 = {0,0,0,0};
            const unsigned short* arow = &encs[it & 3][l15 * ROWSTR + quad * 8];
            #pragma unroll
            for (int ks = 0; ks < 8; ks++) {
                bf16x8 a = __builtin_bit_cast(bf16x8, *(const us8*)(arow + ks * 32));
                acc0 = __builtin_amdgcn_mfma_f32_16x16x32_bf16(a, wf[ks][0], acc0, 0, 0, 0);
                acc1 = __builtin_amdgcn_mfma_f32_16x16x32_bf16(a, wf[ks][1], acc1, 0, 0, 0);
            }
            float p4[4];
            #pragma unroll
            for (int r = 0; r < 4; r++) {
                float t0 = tanh_fast(acc0[r] + hw2v[0]);
                float t1 = tanh_fast(acc1[r] + hw2v[1]);
                p4[r] = betav[0] * t0 + betav[1] * t1;
            }
            #pragma unroll
            for (int m = 1; m < 16; m <<= 1) {
                p4[0] += __shfl_xor(p4[0], m);
                p4[1] += __shfl_xor(p4[1], m);
                p4[2] += __shfl_xor(p4[2], m);
                p4[3] += __shfl_xor(p4[3], m);
            }
            if (l15 == 0) {
                #pragma unroll
                for (int r = 0; r < 4; r++) sp[it & 1][wave][quad * 4 + r] = p4[r];
            }
        }
        // (c) write tile it+1 (regs, loaded last window) into buf (it+1)&3
        if (it < 31)
            *(us8*)&encs[(it + 1) & 3][srow * ROWSTR + scol] = pack8(x0, x1);
        barrier_lgkm();
        x0 = y0; x1 = y1;
    }
    cr[tid] = ctx2;
    barrier_lgkm();
    if (tid == 0) s_part[blk] = ssum;
    if (tid < 128) {
        float2 a0 = cr[tid], a1 = cr[tid + 128], a2 = cr[tid + 256], a3 = cr[tid + 384];
        float2 o;
        o.x = a0.x + a1.x + a2.x + a3.x;
        o.y = a0.y + a1.y + a2.y + a3.y;
        ((float2*)ctx_part)[blk * 128 + tid] = o;   // cols 2t, 2t+1 (unnormalized)
    }
}

// ------------------------------------------------- K4: o_new = tanh([h|ctx] @ W3^T)  (M=256 N=256 K=512), grid 16
// ctx combine fused into A-staging; software-pipelined, 1 lgkm-barrier/iter.
__global__ __launch_bounds__(256) void k_out3(
    const unsigned short* __restrict__ A3u, const float* __restrict__ ctx_part,
    const float* __restrict__ s_part, const float* __restrict__ W3,
    float* __restrict__ out, unsigned short* __restrict__ A4u)
{
    const int m0 = (blockIdx.x >> 2) * 64;
    const int n0 = (blockIdx.x & 3) * 64;
    const int tid = threadIdx.x;
    const int w = tid >> 6, lane = tid & 63, quad = lane >> 4, l15 = lane & 15;
    __shared__ __align__(16) unsigned short As[2][64 * TS];
    __shared__ __align__(16) unsigned short Bs[2][64 * TS];
    f32x4 acc[4] = {{0,0,0,0},{0,0,0,0},{0,0,0,0},{0,0,0,0}};
    const int sm = tid >> 2, sk8 = (tid & 3) * 8;
    const int bb = m0 + sm;
    const float inv = 1.f / (s_part[2 * bb] + s_part[2 * bb + 1]);

    // prologue: tile 0 (k = sk8 < 256 -> A3u path)
    us8 au = *(const us8*)&A3u[bb * 256 + sk8];
    float4 ca0, ca1, cb0, cb1;               // ctx prefetch (kc >= 8)
    float4 wb0, wb1;
    { const float* bp = W3 + (n0 + sm) * 512 + sk8;
      wb0 = *(const float4*)bp; wb1 = *(const float4*)(bp + 4); }

    for (int kc = 0; kc < 16; kc++) {
        const int buf = kc & 1;
        // write tile kc
        if (kc < 8) {
            *(us8*)&As[buf][sm * TS + sk8] = au;
        } else {
            bf16x8 v;
            v[0]=(__bf16)((ca0.x+cb0.x)*inv); v[1]=(__bf16)((ca0.y+cb0.y)*inv);
            v[2]=(__bf16)((ca0.z+cb0.z)*inv); v[3]=(__bf16)((ca0.w+cb0.w)*inv);
            v[4]=(__bf16)((ca1.x+cb1.x)*inv); v[5]=(__bf16)((ca1.y+cb1.y)*inv);
            v[6]=(__bf16)((ca1.z+cb1.z)*inv); v[7]=(__bf16)((ca1.w+cb1.w)*inv);
            *(us8*)&As[buf][sm * TS + sk8] = __builtin_bit_cast(us8, v);
        }
        *(us8*)&Bs[buf][sm * TS + sk8] = pack8(wb0, wb1);
        // prefetch tile kc+1
        if (kc < 15) {
            const int k = (kc + 1) * 32 + sk8;
            if (kc + 1 < 8) {
                au = *(const us8*)&A3u[bb * 256 + k];
            } else {
                const int c = k - 256;
                const float* p0 = ctx_part + (size_t)(2 * bb) * 256 + c;
                const float* p1 = ctx_part + (size_t)(2 * bb + 1) * 256 + c;
                ca0 = *(const float4*)p0; ca1 = *(const float4*)(p0 + 4);
                cb0 = *(const float4*)p1; cb1 = *(const float4*)(p1 + 4);
            }
            const float* bp = W3 + (n0 + sm) * 512 + k;
            wb0 = *(const float4*)bp; wb1 = *(const float4*)(bp + 4);
        }
        barrier_lgkm();
        bf16x8 a = __builtin_bit_cast(bf16x8, *(const us8*)&As[buf][(w * 16 + l15) * TS + quad * 8]);
        #pragma unroll
        for (int nt = 0; nt < 4; nt++) {
            bf16x8 b = __builtin_bit_cast(bf16x8, *(const us8*)&Bs[buf][(nt * 16 + l15) * TS + quad * 8]);
            acc[nt] = __builtin_amdgcn_mfma_f32_16x16x32_bf16(a, b, acc[nt], 0, 0, 0);
        }
    }
    #pragma unroll
    for (int nt = 0; nt < 4; nt++)
        #pragma unroll
        for (int r = 0; r < 4; r++) {
            int row = m0 + w * 16 + quad * 4 + r, col = n0 + nt * 16 + l15;
            float o = tanh_fast(acc[nt][r]);
            out[2 * B_ * H_ + row * 256 + col] = o;   // o_new
            A4u[row * 256 + col] = f2bf(o);
        }
}

// ------------------------------------------------- K5: logit = softmax(o_new @ W_out^T), grid 8
// 32 rows/block (was 64 on grid 4): 2x CU parallelism on a latency-bound kernel.
// Wave = (row-half r2, col-half ch): acc[6] covers 16 rows x 96 cols.
__global__ __launch_bounds__(256) void k_logit(
    const unsigned short* __restrict__ A4u, const float* __restrict__ W_out,
    float* __restrict__ out)
{
    const int m0 = blockIdx.x * 32;
    const int tid = threadIdx.x;
    const int w = tid >> 6, lane = tid & 63, quad = lane >> 4, l15 = lane & 15;
    const int r2 = w >> 1, ch = w & 1;
    __shared__ __align__(16) unsigned short As[2][32 * TS];
    __shared__ __align__(16) unsigned short Bs[2][192 * TS];
    __shared__ float lg[32][196];
    f32x4 acc[6];
    #pragma unroll
    for (int nt = 0; nt < 6; nt++) acc[nt] = (f32x4){0,0,0,0};
    const int sm = tid >> 2, sk8 = (tid & 3) * 8;
    const int j0 = sm, j1 = 64 + sm, j2 = 128 + sm;   // j2 < 172 may fail

    us8 au = {0,0,0,0,0,0,0,0};
    if (tid < 128) au = *(const us8*)&A4u[(m0 + sm) * 256 + sk8];
    float4 w0a, w0b, w1a, w1b, w2a = {0,0,0,0}, w2b = {0,0,0,0};
    { const float* p = W_out + j0 * 256 + sk8; w0a = *(const float4*)p; w0b = *(const float4*)(p + 4); }
    { const float* p = W_out + j1 * 256 + sk8; w1a = *(const float4*)p; w1b = *(const float4*)(p + 4); }
    if (j2 < OUT_) { const float* p = W_out + j2 * 256 + sk8; w2a = *(const float4*)p; w2b = *(const float4*)(p + 4); }

    for (int kc = 0; kc < 8; kc++) {
        const int buf = kc & 1;
        if (tid < 128) *(us8*)&As[buf][sm * TS + sk8] = au;
        *(us8*)&Bs[buf][j0 * TS + sk8] = pack8(w0a, w0b);
        *(us8*)&Bs[buf][j1 * TS + sk8] = pack8(w1a, w1b);
        *(us8*)&Bs[buf][j2 * TS + sk8] = pack8(w2a, w2b);   // zeros when j2 >= OUT_
        if (kc < 7) {
            const int k = (kc + 1) * 32 + sk8;
            if (tid < 128) au = *(const us8*)&A4u[(m0 + sm) * 256 + k];
            { const float* p = W_out + j0 * 256 + k; w0a = *(const float4*)p; w0b = *(const float4*)(p + 4); }
            { const float* p = W_out + j1 * 256 + k; w1a = *(const float4*)p; w1b = *(const float4*)(p + 4); }
            if (j2 < OUT_) { const float* p = W_out + j2 * 256 + k; w2a = *(const float4*)p; w2b = *(const float4*)(p + 4); }
        }
        barrier_lgkm();
        bf16x8 a = __builtin_bit_cast(bf16x8, *(const us8*)&As[buf][(r2 * 16 + l15) * TS + quad * 8]);
        #pragma unroll
        for (int nt = 0; nt < 6; nt++) {
            bf16x8 b = __builtin_bit_cast(bf16x8, *(const us8*)&Bs[buf][(ch * 96 + nt * 16 + l15) * TS + quad * 8]);
            acc[nt] = __builtin_amdgcn_mfma_f32_16x16x32_bf16(a, b, acc[nt], 0, 0, 0);
        }
    }
    #pragma unroll
    for (int nt = 0; nt < 6; nt++)
        #pragma unroll
        for (int r = 0; r < 4; r++)
            lg[r2 * 16 + quad * 4 + r][ch * 96 + nt * 16 + l15] = acc[nt][r];
    __syncthreads();
    const int m = tid >> 2, p = tid & 3;
    if (m < 32) {
        const int cb = p * 43;
        float mx = -1e30f;
        for (int c = 0; c < 43; c++) mx = fmaxf(mx, lg[m][cb + c]);
        mx = fmaxf(mx, __shfl_xor(mx, 1));
        mx = fmaxf(mx, __shfl_xor(mx, 2));
        float s = 0.f;
        for (int c = 0; c < 43; c++) { float e = __expf(lg[m][cb + c] - mx); lg[m][cb + c] = e; s += e; }
        s += __shfl_xor(s, 1);
        s += __shfl_xor(s, 2);
        float inv = 1.f / s;
        for (int c = 0; c < 43; c++)
            out[3 * B_ * H_ + (m0 + m) * OUT_ + cb + c] = lg[m][cb + c] * inv;
    }
}

// ------------------------------------------------- host
extern "C" void kernel_launch(void* const* d_in, const int* in_sizes, int n_in,
                              void* d_out, int out_size, void* d_ws, size_t ws_size,
                              hipStream_t stream)
{
    const float* h0   = (const float*)d_in[0];
    const float* c0   = (const float*)d_in[1];
    const float* o_t  = (const float*)d_in[2];
    const float* enc  = (const float*)d_in[3];
    const int*   lt   = (const int*)  d_in[4];
    const float* emb  = (const float*)d_in[5];
    const float* W_ih = (const float*)d_in[6];
    const float* W_hh = (const float*)d_in[7];
    const float* b_ih = (const float*)d_in[8];
    const float* b_hh = (const float*)d_in[9];
    const float* W1   = (const float*)d_in[10];
    const float* W2   = (const float*)d_in[11];
    const float* W3   = (const float*)d_in[12];
    const float* Wo   = (const float*)d_in[13];
    const float* beta = (const float*)d_in[14];
    float* out = (float*)d_out;
    float* ws  = (float*)d_ws;

    float*          gates    = ws;                               // 256*1024 f32
    float*          hW2      = ws + 262144;                      // 256*256 f32
    float*          ctx_part = ws + 327680;                      // 512*256 f32
    float*          s_part   = ws + 458752;                      // 512 f32
    unsigned short* A3u      = (unsigned short*)(ws + 459264);   // 256*256 bf16 (h)
    unsigned short* A4u      = (unsigned short*)(ws + 492032);   // 256*256 bf16 (o_new)

    k_gates<<<64, 256, 0, stream>>>(h0, o_t, lt, emb, W_ih, W_hh, b_ih, b_hh, gates);
    k_lstm <<<256, 256, 0, stream>>>(gates, c0, W2, out, A3u, hW2);
    k_attn <<<512, 512, 0, stream>>>(enc, W1, hW2, beta, ctx_part, s_part);
    k_out3 <<<16, 256, 0, stream>>>(A3u, ctx_part, s_part, W3, out, A4u);
    k_logit<<<8, 256, 0, stream>>>(A4u, Wo, out);
}